// Round 17
// baseline (571.402 us; speedup 1.0000x reference)
//
#include <hip/hip_runtime.h>

#define N 1024
#define D 64
#define EPS 1e-12f
#define LAMBDA 2097152.0f   // 2^21; relu(l*x)=l*relu(x), row-L1 normalize kills it
#define MAGIC 0x7F3A21C5u

typedef float f32x4 __attribute__((ext_vector_type(4)));
typedef __fp16 h2 __attribute__((ext_vector_type(2)));       // cvt_pkrtz result type
typedef _Float16 f16x2 __attribute__((ext_vector_type(2)));  // fdot2 operand type
typedef unsigned u32x4 __attribute__((ext_vector_type(4)));

union H2U { h2 h; f16x2 f; unsigned u; };

__device__ __forceinline__ float rfl(float x) {
    return __uint_as_float(__builtin_amdgcn_readfirstlane(__float_as_uint(x)));
}

// ---------------- K1: colsum (f32, R12-proven, unchanged) ----------------
__global__ __launch_bounds__(256) void colsum_kernel(
        const float* __restrict__ z1, const float* __restrict__ z2,
        float* __restrict__ partial) {
    int b  = blockIdx.x;
    int jq = b & 3;
    int ib = (b >> 2) & 63;
    int m  = b >> 8;
    const float4* z4 = reinterpret_cast<const float4*>(m ? z2 : z1);
    __shared__ float4 zs[256 * 16];
    __shared__ float4 red[4][4][16];
    int tid = threadIdx.x;
    int j0 = jq * 256;
    #pragma unroll
    for (int k = 0; k < 16; ++k) {
        int idx = k * 256 + tid;
        zs[idx] = z4[(j0 + (idx >> 4)) * 16 + (idx & 15)];
    }
    int w  = tid >> 6;
    int l  = tid & 63;
    int cq = l & 15;
    int jg = l >> 4;
    int i0 = ib * 16 + w * 4;
    float4 a[4];
    #pragma unroll
    for (int r = 0; r < 4; ++r) a[r] = z4[(i0 + r) * 16 + cq];
    float4 s[4];
    #pragma unroll
    for (int r = 0; r < 4; ++r) s[r] = make_float4(0.f, 0.f, 0.f, 0.f);
    __syncthreads();
    #pragma unroll 8
    for (int js = 0; js < 64; ++js) {
        float4 v = zs[(js * 4 + jg) * 16 + cq];
        #pragma unroll
        for (int r = 0; r < 4; ++r) {
            s[r].x += fabsf(a[r].x - v.x);
            s[r].y += fabsf(a[r].y - v.y);
            s[r].z += fabsf(a[r].z - v.z);
            s[r].w += fabsf(a[r].w - v.w);
        }
    }
    #pragma unroll
    for (int r = 0; r < 4; ++r) {
        s[r].x += __shfl_xor(s[r].x, 16, 64);
        s[r].y += __shfl_xor(s[r].y, 16, 64);
        s[r].z += __shfl_xor(s[r].z, 16, 64);
        s[r].w += __shfl_xor(s[r].w, 16, 64);
        s[r].x += __shfl_xor(s[r].x, 32, 64);
        s[r].y += __shfl_xor(s[r].y, 32, 64);
        s[r].z += __shfl_xor(s[r].z, 32, 64);
        s[r].w += __shfl_xor(s[r].w, 32, 64);
    }
    if (l < 16) {
        red[w][0][l] = s[0]; red[w][1][l] = s[1];
        red[w][2][l] = s[2]; red[w][3][l] = s[3];
    }
    __syncthreads();
    if (tid < 16) {
        float4 t = make_float4(0.f, 0.f, 0.f, 0.f);
        #pragma unroll
        for (int ww = 0; ww < 4; ++ww)
            #pragma unroll
            for (int r = 0; r < 4; ++r) {
                float4 q = red[ww][r][tid];
                t.x += q.x; t.y += q.y; t.z += q.z; t.w += q.w;
            }
        reinterpret_cast<float4*>(partial)[(m * 256 + jq * 64 + ib) * 16 + tid] = t;
    }
}

// ---------------- K2: merged proj (blocks 0..127) + pair (blocks 128..1151) ----------------
union ShMem {
    struct { float invS[64]; float sW[64 * 64]; float zs[16][64]; float redS[4][64]; } p2;
    struct { float red[2][4]; } p3;
};

__global__ __launch_bounds__(256) void projpair_kernel(
        const float* __restrict__ z1, const float* __restrict__ z2,
        const float* __restrict__ W1, const float* __restrict__ b1,
        const float* __restrict__ W2, const float* __restrict__ b2,
        const float* __restrict__ partial,
        unsigned* __restrict__ pTh2, unsigned* __restrict__ pbh2,
        unsigned* __restrict__ flags,
        float* __restrict__ out) {
    __shared__ ShMem sh;
    int blk = blockIdx.x;
    int tid = threadIdx.x;

    if (blk < 128) {
        // ===== proj role (R16 body verbatim) =====
        int m  = blk >> 6;
        int rb = blk & 63;
        int i0 = rb * 16;
        const float* z = m ? z2 : z1;
        int c = tid & 63, chunk = tid >> 6;
        float ssum = 0.f;
        for (int k = 0; k < 64; ++k)
            ssum += partial[(m * 256 + chunk * 64 + k) * 64 + c];
        sh.p2.redS[chunk][c] = ssum;
        for (int idx = tid; idx < 16 * 64; idx += 256)
            sh.p2.zs[idx >> 6][idx & 63] = z[(i0 + (idx >> 6)) * 64 + (idx & 63)];
        __syncthreads();
        if (tid < 64)
            sh.p2.invS[tid] = LAMBDA / fmaxf(sh.p2.redS[0][tid] + sh.p2.redS[1][tid] +
                                             sh.p2.redS[2][tid] + sh.p2.redS[3][tid], EPS);
        __syncthreads();
        for (int idx = tid; idx < 64 * 64; idx += 256)
            sh.p2.sW[idx] = W1[idx] * sh.p2.invS[idx >> 6];
        __syncthreads();
        float acc[4] = {0.f, 0.f, 0.f, 0.f};
        for (int k = 0; k < 64; ++k) {
            float wv = sh.p2.sW[k * 64 + c];
            #pragma unroll
            for (int q = 0; q < 4; ++q) acc[q] += sh.p2.zs[chunk + 4 * q][k] * wv;
        }
        float lb1 = b1[c] * LAMBDA;
        #pragma unroll
        for (int q = 0; q < 4; ++q) {
            int row = i0 + chunk + 4 * q;
            float mine = acc[q];
            float part = __shfl_xor(mine, 1, 64);
            float pbm  = mine + lb1;
            float pbp  = __shfl_xor(pbm, 1, 64);
            if ((c & 1) == 0) {
                H2U t;  t.h  = __builtin_amdgcn_cvt_pkrtz(mine, part);
                H2U tb; tb.h = __builtin_amdgcn_cvt_pkrtz(pbm, pbp);
                pTh2[(m * 32 + (c >> 1)) * N + row] = t.u;
                pbh2[(m * N + row) * 32 + (c >> 1)] = tb.u;
            }
        }
        // release: all global writes visible before flag
        __threadfence();
        __syncthreads();
        if (tid == 0)
            __hip_atomic_store(&flags[blk], MAGIC, __ATOMIC_RELEASE, __HIP_MEMORY_SCOPE_AGENT);
        return;
    }

    // ===== pair role (R16 body; waits for its plane's 64 proj flags) =====
    int pb = blk - 128;
    int m  = pb >> 9;
    int rb = pb & 511;
    int i0 = rb * 2;

    if (tid == 0) {
        for (int p = 0; p < 64; ++p) {
            while (__hip_atomic_load(&flags[m * 64 + p], __ATOMIC_ACQUIRE,
                                     __HIP_MEMORY_SCOPE_AGENT) != MAGIC) {
                __builtin_amdgcn_s_sleep(8);
            }
        }
    }
    __syncthreads();
    __threadfence();

    const unsigned* uT = pTh2 + (size_t)m * 32 * N;
    const unsigned* vb = pbh2 + ((size_t)m * N + i0) * 32;
    h2 zero = {(__fp16)0, (__fp16)0};

    unsigned sw2[32];
    #pragma unroll
    for (int cp = 0; cp < 32; ++cp) {
        H2U t; t.h = __builtin_amdgcn_cvt_pkrtz(W2[2 * cp], W2[2 * cp + 1]);
        sw2[cp] = __builtin_amdgcn_readfirstlane(t.u);
    }
    float b2l = rfl(b2[0]) * LAMBDA;

    float acc[4][2];
    #pragma unroll
    for (int q = 0; q < 4; ++q)
        #pragma unroll
        for (int r = 0; r < 2; ++r) acc[q][r] = 0.f;

    #pragma unroll 8
    for (int cp = 0; cp < 32; ++cp) {
        u32x4 uu = reinterpret_cast<const u32x4*>(uT + (size_t)cp * N)[tid];
        H2U w; w.u = sw2[cp];
        H2U u0, u1, u2, u3;
        u0.u = uu.x; u1.u = uu.y; u2.u = uu.z; u3.u = uu.w;
        #pragma unroll
        for (int r = 0; r < 2; ++r) {
            H2U a; a.u = __builtin_amdgcn_readfirstlane(vb[r * 32 + cp]);
            H2U d0, d1, d2, d3;
            d0.h = __builtin_elementwise_max(a.h - u0.h, zero);
            d1.h = __builtin_elementwise_max(a.h - u1.h, zero);
            d2.h = __builtin_elementwise_max(a.h - u2.h, zero);
            d3.h = __builtin_elementwise_max(a.h - u3.h, zero);
            acc[0][r] = __builtin_amdgcn_fdot2(d0.f, w.f, acc[0][r], false);
            acc[1][r] = __builtin_amdgcn_fdot2(d1.f, w.f, acc[1][r], false);
            acc[2][r] = __builtin_amdgcn_fdot2(d2.f, w.f, acc[2][r], false);
            acc[3][r] = __builtin_amdgcn_fdot2(d3.f, w.f, acc[3][r], false);
        }
    }

    float o[4][2];
    float psum[2];
    #pragma unroll
    for (int r = 0; r < 2; ++r) {
        float s = 0.f;
        #pragma unroll
        for (int q = 0; q < 4; ++q) {
            o[q][r] = fmaxf(acc[q][r] + b2l, 0.f);
            s += o[q][r];
        }
        #pragma unroll
        for (int off = 32; off; off >>= 1) s += __shfl_down(s, off, 64);
        psum[r] = s;
    }
    int lane = tid & 63, wv = tid >> 6;
    if (lane == 0) {
        sh.p3.red[0][wv] = psum[0]; sh.p3.red[1][wv] = psum[1];
    }
    __syncthreads();
    size_t plane = (size_t)N * N;
    #pragma unroll
    for (int r = 0; r < 2; ++r) {
        float inv = 1.f / fmaxf(sh.p3.red[r][0] + sh.p3.red[r][1] +
                                sh.p3.red[r][2] + sh.p3.red[r][3], EPS);
        f32x4 v4 = {o[0][r] * inv, o[1][r] * inv, o[2][r] * inv, o[3][r] * inv};
        float* dst = out + (size_t)m * plane + (size_t)(i0 + r) * N + 4 * tid;
        __builtin_nontemporal_store(v4, reinterpret_cast<f32x4*>(dst));
        __builtin_nontemporal_store(v4, reinterpret_cast<f32x4*>(dst + 2 * plane));
    }
}

extern "C" void kernel_launch(void* const* d_in, const int* in_sizes, int n_in,
                              void* d_out, int out_size, void* d_ws, size_t ws_size,
                              hipStream_t stream) {
    const float* z1 = (const float*)d_in[0];
    const float* z2 = (const float*)d_in[1];
    const float* W1 = (const float*)d_in[2];
    const float* b1 = (const float*)d_in[3];
    const float* W2 = (const float*)d_in[4];
    const float* b2 = (const float*)d_in[5];
    float* out = (float*)d_out;

    float* partial = (float*)d_ws;                   // [2][256][64] = 32768 floats
    unsigned* pTh2 = (unsigned*)(partial + 32768);   // [2][32][1024] = 65536 uints
    unsigned* pbh2 = pTh2 + 65536;                   // [2][1024][32] = 65536 uints
    unsigned* flags = pbh2 + 65536;                  // [128] uints

    colsum_kernel<<<512, 256, 0, stream>>>(z1, z2, partial);
    projpair_kernel<<<1152, 256, 0, stream>>>(z1, z2, W1, b1, W2, b2,
                                              partial, pTh2, pbh2, flags, out);
}

// Round 18
// 36.160 us; speedup vs baseline: 15.8020x; 15.8020x over previous
//
#include <hip/hip_runtime.h>

#define N 1024
#define D 64
#define EPS 1e-12f
#define LAMBDA 2097152.0f   // 2^21; relu(l*x)=l*relu(x), row-L1 normalize kills it

typedef float f32x4 __attribute__((ext_vector_type(4)));
typedef __fp16 h2 __attribute__((ext_vector_type(2)));       // cvt_pkrtz result type
typedef _Float16 f16x2 __attribute__((ext_vector_type(2)));  // fdot2 operand type
typedef unsigned u32x4 __attribute__((ext_vector_type(4)));

union H2U { h2 h; f16x2 f; unsigned u; };

__device__ __forceinline__ float rfl(float x) {
    return __uint_as_float(__builtin_amdgcn_readfirstlane(__float_as_uint(x)));
}

// ---------------- K1: colsum (LDS-free; z is L2-resident broadcast) ----------------
// partial[m][blk][c], blk = jq*64 + ib; block covers 16 i-rows x 256 j-rows.
__global__ __launch_bounds__(256) void colsum_kernel(
        const float* __restrict__ z1, const float* __restrict__ z2,
        float* __restrict__ partial) {
    int b  = blockIdx.x;
    int jq = b & 3;
    int ib = (b >> 2) & 63;
    int m  = b >> 8;
    const float4* z4 = reinterpret_cast<const float4*>(m ? z2 : z1);
    __shared__ float4 red[16][16];   // [w*4+r][cq] -- 4KB only
    int tid = threadIdx.x;
    int w  = tid >> 6;
    int l  = tid & 63;
    int cq = l & 15;           // c-quad 0..15
    int jg = l >> 4;           // j-group 0..3
    int i0 = ib * 16 + w * 4;
    float4 a[4];
    #pragma unroll
    for (int r = 0; r < 4; ++r) a[r] = z4[(i0 + r) * 16 + cq];
    float4 s[4];
    #pragma unroll
    for (int r = 0; r < 4; ++r) s[r] = make_float4(0.f, 0.f, 0.f, 0.f);
    int j0 = jq * 256;
    #pragma unroll 8
    for (int js = 0; js < 64; ++js) {
        float4 v = z4[(j0 + js * 4 + jg) * 16 + cq];   // direct L2 read, wave-coalesced
        #pragma unroll
        for (int r = 0; r < 4; ++r) {
            s[r].x += fabsf(a[r].x - v.x);
            s[r].y += fabsf(a[r].y - v.y);
            s[r].z += fabsf(a[r].z - v.z);
            s[r].w += fabsf(a[r].w - v.w);
        }
    }
    #pragma unroll
    for (int r = 0; r < 4; ++r) {
        s[r].x += __shfl_xor(s[r].x, 16, 64);
        s[r].y += __shfl_xor(s[r].y, 16, 64);
        s[r].z += __shfl_xor(s[r].z, 16, 64);
        s[r].w += __shfl_xor(s[r].w, 16, 64);
        s[r].x += __shfl_xor(s[r].x, 32, 64);
        s[r].y += __shfl_xor(s[r].y, 32, 64);
        s[r].z += __shfl_xor(s[r].z, 32, 64);
        s[r].w += __shfl_xor(s[r].w, 32, 64);
    }
    if (l < 16) {
        #pragma unroll
        for (int r = 0; r < 4; ++r) red[w * 4 + r][l] = s[r];
    }
    __syncthreads();
    if (tid < 16) {
        float4 t = make_float4(0.f, 0.f, 0.f, 0.f);
        #pragma unroll
        for (int k = 0; k < 16; ++k) {
            float4 q = red[k][tid];
            t.x += q.x; t.y += q.y; t.z += q.z; t.w += q.w;
        }
        reinterpret_cast<float4*>(partial)[(m * 256 + jq * 64 + ib) * 16 + tid] = t;
    }
}

// ---------------- K2: proj (R12-proven, unchanged) ----------------
__global__ __launch_bounds__(256) void proj_kernel(
        const float* __restrict__ z1, const float* __restrict__ z2,
        const float* __restrict__ W1, const float* __restrict__ b1,
        const float* __restrict__ partial,
        unsigned* __restrict__ pTh2, unsigned* __restrict__ pbh2) {
    int m  = blockIdx.x >> 6;
    int rb = blockIdx.x & 63;
    int i0 = rb * 16;
    const float* z = m ? z2 : z1;
    __shared__ float invS[64];
    __shared__ float sW[64 * 64];
    __shared__ float zs[16][64];
    __shared__ float redS[4][64];
    int tid = threadIdx.x;
    int c = tid & 63, chunk = tid >> 6;
    float ssum = 0.f;
    for (int k = 0; k < 64; ++k)
        ssum += partial[(m * 256 + chunk * 64 + k) * 64 + c];
    redS[chunk][c] = ssum;
    for (int idx = tid; idx < 16 * 64; idx += 256)
        zs[idx >> 6][idx & 63] = z[(i0 + (idx >> 6)) * 64 + (idx & 63)];
    __syncthreads();
    if (tid < 64)
        invS[tid] = LAMBDA / fmaxf(redS[0][tid] + redS[1][tid] + redS[2][tid] + redS[3][tid], EPS);
    __syncthreads();
    for (int idx = tid; idx < 64 * 64; idx += 256)
        sW[idx] = W1[idx] * invS[idx >> 6];
    __syncthreads();
    float acc[4] = {0.f, 0.f, 0.f, 0.f};
    for (int k = 0; k < 64; ++k) {
        float wv = sW[k * 64 + c];
        #pragma unroll
        for (int q = 0; q < 4; ++q) acc[q] += zs[chunk + 4 * q][k] * wv;
    }
    float lb1 = b1[c] * LAMBDA;
    #pragma unroll
    for (int q = 0; q < 4; ++q) {
        int row = i0 + chunk + 4 * q;
        float mine = acc[q];
        float part = __shfl_xor(mine, 1, 64);
        float pbm  = mine + lb1;
        float pbp  = __shfl_xor(pbm, 1, 64);
        if ((c & 1) == 0) {
            H2U t;  t.h  = __builtin_amdgcn_cvt_pkrtz(mine, part);
            H2U tb; tb.h = __builtin_amdgcn_cvt_pkrtz(pbm, pbp);
            pTh2[(m * 32 + (c >> 1)) * N + row] = t.u;
            pbh2[(m * N + row) * 32 + (c >> 1)] = tb.u;
        }
    }
}

// ---------------- K3: pair scores (R16-proven, unchanged) ----------------
__global__ __launch_bounds__(256) void pair_kernel(
        const unsigned* __restrict__ pTh2,  // [2][32][N]
        const unsigned* __restrict__ pbh2,  // [2][N][32]
        const float* __restrict__ W2, const float* __restrict__ b2,
        float* __restrict__ out) {
    int m  = blockIdx.x >> 9;
    int rb = blockIdx.x & 511;
    int i0 = rb * 2;
    const unsigned* uT = pTh2 + (size_t)m * 32 * N;
    const unsigned* vb = pbh2 + ((size_t)m * N + i0) * 32;
    int tid = threadIdx.x;
    h2 zero = {(__fp16)0, (__fp16)0};

    unsigned sw2[32];
    #pragma unroll
    for (int cp = 0; cp < 32; ++cp) {
        H2U t; t.h = __builtin_amdgcn_cvt_pkrtz(W2[2 * cp], W2[2 * cp + 1]);
        sw2[cp] = __builtin_amdgcn_readfirstlane(t.u);
    }
    float b2l = rfl(b2[0]) * LAMBDA;

    float acc[4][2];  // [q][r], this thread's j = 4*tid + q
    #pragma unroll
    for (int q = 0; q < 4; ++q)
        #pragma unroll
        for (int r = 0; r < 2; ++r) acc[q][r] = 0.f;

    #pragma unroll 8
    for (int cp = 0; cp < 32; ++cp) {
        u32x4 uu = reinterpret_cast<const u32x4*>(uT + (size_t)cp * N)[tid];
        H2U w; w.u = sw2[cp];
        H2U u0, u1, u2, u3;
        u0.u = uu.x; u1.u = uu.y; u2.u = uu.z; u3.u = uu.w;
        #pragma unroll
        for (int r = 0; r < 2; ++r) {
            H2U a; a.u = __builtin_amdgcn_readfirstlane(vb[r * 32 + cp]);
            H2U d0, d1, d2, d3;
            d0.h = __builtin_elementwise_max(a.h - u0.h, zero);
            d1.h = __builtin_elementwise_max(a.h - u1.h, zero);
            d2.h = __builtin_elementwise_max(a.h - u2.h, zero);
            d3.h = __builtin_elementwise_max(a.h - u3.h, zero);
            acc[0][r] = __builtin_amdgcn_fdot2(d0.f, w.f, acc[0][r], false);
            acc[1][r] = __builtin_amdgcn_fdot2(d1.f, w.f, acc[1][r], false);
            acc[2][r] = __builtin_amdgcn_fdot2(d2.f, w.f, acc[2][r], false);
            acc[3][r] = __builtin_amdgcn_fdot2(d3.f, w.f, acc[3][r], false);
        }
    }

    float o[4][2];
    float psum[2];
    __shared__ float red[2][4];
    #pragma unroll
    for (int r = 0; r < 2; ++r) {
        float s = 0.f;
        #pragma unroll
        for (int q = 0; q < 4; ++q) {
            o[q][r] = fmaxf(acc[q][r] + b2l, 0.f);
            s += o[q][r];
        }
        #pragma unroll
        for (int off = 32; off; off >>= 1) s += __shfl_down(s, off, 64);
        psum[r] = s;
    }
    int lane = tid & 63, wv = tid >> 6;
    if (lane == 0) {
        red[0][wv] = psum[0]; red[1][wv] = psum[1];
    }
    __syncthreads();
    size_t plane = (size_t)N * N;
    #pragma unroll
    for (int r = 0; r < 2; ++r) {
        float inv = 1.f / fmaxf(red[r][0] + red[r][1] + red[r][2] + red[r][3], EPS);
        f32x4 v4 = {o[0][r] * inv, o[1][r] * inv, o[2][r] * inv, o[3][r] * inv};
        float* dst = out + (size_t)m * plane + (size_t)(i0 + r) * N + 4 * tid;
        __builtin_nontemporal_store(v4, reinterpret_cast<f32x4*>(dst));
        __builtin_nontemporal_store(v4, reinterpret_cast<f32x4*>(dst + 2 * plane));
    }
}

extern "C" void kernel_launch(void* const* d_in, const int* in_sizes, int n_in,
                              void* d_out, int out_size, void* d_ws, size_t ws_size,
                              hipStream_t stream) {
    const float* z1 = (const float*)d_in[0];
    const float* z2 = (const float*)d_in[1];
    const float* W1 = (const float*)d_in[2];
    const float* b1 = (const float*)d_in[3];
    const float* W2 = (const float*)d_in[4];
    const float* b2 = (const float*)d_in[5];
    float* out = (float*)d_out;

    float* partial = (float*)d_ws;                   // [2][256][64] = 32768 floats
    unsigned* pTh2 = (unsigned*)(partial + 32768);   // [2][32][1024] = 65536 uints
    unsigned* pbh2 = pTh2 + 65536;                   // [2][1024][32] = 65536 uints

    colsum_kernel<<<512, 256, 0, stream>>>(z1, z2, partial);
    proj_kernel<<<128, 256, 0, stream>>>(z1, z2, W1, b1, partial, pTh2, pbh2);
    pair_kernel<<<1024, 256, 0, stream>>>(pTh2, pbh2, W2, b2, out);
}

// Round 19
// 32.407 us; speedup vs baseline: 17.6320x; 1.1158x over previous
//
#include <hip/hip_runtime.h>

#define N 1024
#define D 64
#define EPS 1e-12f
#define LAMBDA 2097152.0f   // 2^21; relu(l*x)=l*relu(x), row-L1 normalize kills it

typedef float f32x4 __attribute__((ext_vector_type(4)));
typedef __fp16 h2 __attribute__((ext_vector_type(2)));       // cvt_pkrtz result type
typedef _Float16 f16x2 __attribute__((ext_vector_type(2)));  // fdot2 operand type
typedef unsigned u32x4 __attribute__((ext_vector_type(4)));

union H2U { h2 h; f16x2 f; unsigned u; };

__device__ __forceinline__ float rfl(float x) {
    return __uint_as_float(__builtin_amdgcn_readfirstlane(__float_as_uint(x)));
}

// ---------------- K1: colsum (f32, LDS-staged, R12/R16-proven) ----------------
__global__ __launch_bounds__(256) void colsum_kernel(
        const float* __restrict__ z1, const float* __restrict__ z2,
        float* __restrict__ partial) {
    int b  = blockIdx.x;
    int jq = b & 3;
    int ib = (b >> 2) & 63;
    int m  = b >> 8;
    const float4* z4 = reinterpret_cast<const float4*>(m ? z2 : z1);
    __shared__ float4 zs[256 * 16];
    __shared__ float4 red[4][4][16];
    int tid = threadIdx.x;
    int j0 = jq * 256;
    #pragma unroll
    for (int k = 0; k < 16; ++k) {
        int idx = k * 256 + tid;
        zs[idx] = z4[(j0 + (idx >> 4)) * 16 + (idx & 15)];
    }
    int w  = tid >> 6;
    int l  = tid & 63;
    int cq = l & 15;
    int jg = l >> 4;
    int i0 = ib * 16 + w * 4;
    float4 a[4];
    #pragma unroll
    for (int r = 0; r < 4; ++r) a[r] = z4[(i0 + r) * 16 + cq];
    float4 s[4];
    #pragma unroll
    for (int r = 0; r < 4; ++r) s[r] = make_float4(0.f, 0.f, 0.f, 0.f);
    __syncthreads();
    #pragma unroll 8
    for (int js = 0; js < 64; ++js) {
        float4 v = zs[(js * 4 + jg) * 16 + cq];
        #pragma unroll
        for (int r = 0; r < 4; ++r) {
            s[r].x += fabsf(a[r].x - v.x);
            s[r].y += fabsf(a[r].y - v.y);
            s[r].z += fabsf(a[r].z - v.z);
            s[r].w += fabsf(a[r].w - v.w);
        }
    }
    #pragma unroll
    for (int r = 0; r < 4; ++r) {
        s[r].x += __shfl_xor(s[r].x, 16, 64);
        s[r].y += __shfl_xor(s[r].y, 16, 64);
        s[r].z += __shfl_xor(s[r].z, 16, 64);
        s[r].w += __shfl_xor(s[r].w, 16, 64);
        s[r].x += __shfl_xor(s[r].x, 32, 64);
        s[r].y += __shfl_xor(s[r].y, 32, 64);
        s[r].z += __shfl_xor(s[r].z, 32, 64);
        s[r].w += __shfl_xor(s[r].w, 32, 64);
    }
    if (l < 16) {
        red[w][0][l] = s[0]; red[w][1][l] = s[1];
        red[w][2][l] = s[2]; red[w][3][l] = s[3];
    }
    __syncthreads();
    if (tid < 16) {
        float4 t = make_float4(0.f, 0.f, 0.f, 0.f);
        #pragma unroll
        for (int ww = 0; ww < 4; ++ww)
            #pragma unroll
            for (int r = 0; r < 4; ++r) {
                float4 q = red[ww][r][tid];
                t.x += q.x; t.y += q.y; t.z += q.z; t.w += q.w;
            }
        reinterpret_cast<float4*>(partial)[(m * 256 + jq * 64 + ib) * 16 + tid] = t;
    }
}

// ---------------- K2: proj (R12-proven, unchanged) ----------------
__global__ __launch_bounds__(256) void proj_kernel(
        const float* __restrict__ z1, const float* __restrict__ z2,
        const float* __restrict__ W1, const float* __restrict__ b1,
        const float* __restrict__ partial,
        unsigned* __restrict__ pTh2, unsigned* __restrict__ pbh2) {
    int m  = blockIdx.x >> 6;
    int rb = blockIdx.x & 63;
    int i0 = rb * 16;
    const float* z = m ? z2 : z1;
    __shared__ float invS[64];
    __shared__ float sW[64 * 64];
    __shared__ float zs[16][64];
    __shared__ float redS[4][64];
    int tid = threadIdx.x;
    int c = tid & 63, chunk = tid >> 6;
    float ssum = 0.f;
    for (int k = 0; k < 64; ++k)
        ssum += partial[(m * 256 + chunk * 64 + k) * 64 + c];
    redS[chunk][c] = ssum;
    for (int idx = tid; idx < 16 * 64; idx += 256)
        zs[idx >> 6][idx & 63] = z[(i0 + (idx >> 6)) * 64 + (idx & 63)];
    __syncthreads();
    if (tid < 64)
        invS[tid] = LAMBDA / fmaxf(redS[0][tid] + redS[1][tid] + redS[2][tid] + redS[3][tid], EPS);
    __syncthreads();
    for (int idx = tid; idx < 64 * 64; idx += 256)
        sW[idx] = W1[idx] * invS[idx >> 6];
    __syncthreads();
    float acc[4] = {0.f, 0.f, 0.f, 0.f};
    for (int k = 0; k < 64; ++k) {
        float wv = sW[k * 64 + c];
        #pragma unroll
        for (int q = 0; q < 4; ++q) acc[q] += zs[chunk + 4 * q][k] * wv;
    }
    float lb1 = b1[c] * LAMBDA;
    #pragma unroll
    for (int q = 0; q < 4; ++q) {
        int row = i0 + chunk + 4 * q;
        float mine = acc[q];
        float part = __shfl_xor(mine, 1, 64);
        float pbm  = mine + lb1;
        float pbp  = __shfl_xor(pbm, 1, 64);
        if ((c & 1) == 0) {
            H2U t;  t.h  = __builtin_amdgcn_cvt_pkrtz(mine, part);
            H2U tb; tb.h = __builtin_amdgcn_cvt_pkrtz(pbm, pbp);
            pTh2[(m * 32 + (c >> 1)) * N + row] = t.u;
            pbh2[(m * N + row) * 32 + (c >> 1)] = tb.u;
        }
    }
}

// ---------------- K3: pair scores (R16-proven, unchanged) ----------------
__global__ __launch_bounds__(256) void pair_kernel(
        const unsigned* __restrict__ pTh2,  // [2][32][N]
        const unsigned* __restrict__ pbh2,  // [2][N][32]
        const float* __restrict__ W2, const float* __restrict__ b2,
        float* __restrict__ out) {
    int m  = blockIdx.x >> 9;
    int rb = blockIdx.x & 511;
    int i0 = rb * 2;
    const unsigned* uT = pTh2 + (size_t)m * 32 * N;
    const unsigned* vb = pbh2 + ((size_t)m * N + i0) * 32;
    int tid = threadIdx.x;
    h2 zero = {(__fp16)0, (__fp16)0};

    unsigned sw2[32];
    #pragma unroll
    for (int cp = 0; cp < 32; ++cp) {
        H2U t; t.h = __builtin_amdgcn_cvt_pkrtz(W2[2 * cp], W2[2 * cp + 1]);
        sw2[cp] = __builtin_amdgcn_readfirstlane(t.u);
    }
    float b2l = rfl(b2[0]) * LAMBDA;

    float acc[4][2];  // [q][r], this thread's j = 4*tid + q
    #pragma unroll
    for (int q = 0; q < 4; ++q)
        #pragma unroll
        for (int r = 0; r < 2; ++r) acc[q][r] = 0.f;

    #pragma unroll 8
    for (int cp = 0; cp < 32; ++cp) {
        u32x4 uu = reinterpret_cast<const u32x4*>(uT + (size_t)cp * N)[tid];
        H2U w; w.u = sw2[cp];
        H2U u0, u1, u2, u3;
        u0.u = uu.x; u1.u = uu.y; u2.u = uu.z; u3.u = uu.w;
        #pragma unroll
        for (int r = 0; r < 2; ++r) {
            H2U a; a.u = __builtin_amdgcn_readfirstlane(vb[r * 32 + cp]);
            H2U d0, d1, d2, d3;
            d0.h = __builtin_elementwise_max(a.h - u0.h, zero);
            d1.h = __builtin_elementwise_max(a.h - u1.h, zero);
            d2.h = __builtin_elementwise_max(a.h - u2.h, zero);
            d3.h = __builtin_elementwise_max(a.h - u3.h, zero);
            acc[0][r] = __builtin_amdgcn_fdot2(d0.f, w.f, acc[0][r], false);
            acc[1][r] = __builtin_amdgcn_fdot2(d1.f, w.f, acc[1][r], false);
            acc[2][r] = __builtin_amdgcn_fdot2(d2.f, w.f, acc[2][r], false);
            acc[3][r] = __builtin_amdgcn_fdot2(d3.f, w.f, acc[3][r], false);
        }
    }

    float o[4][2];
    float psum[2];
    __shared__ float red[2][4];
    #pragma unroll
    for (int r = 0; r < 2; ++r) {
        float s = 0.f;
        #pragma unroll
        for (int q = 0; q < 4; ++q) {
            o[q][r] = fmaxf(acc[q][r] + b2l, 0.f);
            s += o[q][r];
        }
        #pragma unroll
        for (int off = 32; off; off >>= 1) s += __shfl_down(s, off, 64);
        psum[r] = s;
    }
    int lane = tid & 63, wv = tid >> 6;
    if (lane == 0) {
        red[0][wv] = psum[0]; red[1][wv] = psum[1];
    }
    __syncthreads();
    size_t plane = (size_t)N * N;
    #pragma unroll
    for (int r = 0; r < 2; ++r) {
        float inv = 1.f / fmaxf(red[r][0] + red[r][1] + red[r][2] + red[r][3], EPS);
        f32x4 v4 = {o[0][r] * inv, o[1][r] * inv, o[2][r] * inv, o[3][r] * inv};
        float* dst = out + (size_t)m * plane + (size_t)(i0 + r) * N + 4 * tid;
        __builtin_nontemporal_store(v4, reinterpret_cast<f32x4*>(dst));
        __builtin_nontemporal_store(v4, reinterpret_cast<f32x4*>(dst + 2 * plane));
    }
}

extern "C" void kernel_launch(void* const* d_in, const int* in_sizes, int n_in,
                              void* d_out, int out_size, void* d_ws, size_t ws_size,
                              hipStream_t stream) {
    const float* z1 = (const float*)d_in[0];
    const float* z2 = (const float*)d_in[1];
    const float* W1 = (const float*)d_in[2];
    const float* b1 = (const float*)d_in[3];
    const float* W2 = (const float*)d_in[4];
    const float* b2 = (const float*)d_in[5];
    float* out = (float*)d_out;

    float* partial = (float*)d_ws;                   // [2][256][64] = 32768 floats
    unsigned* pTh2 = (unsigned*)(partial + 32768);   // [2][32][1024] = 65536 uints
    unsigned* pbh2 = pTh2 + 65536;                   // [2][1024][32] = 65536 uints

    colsum_kernel<<<512, 256, 0, stream>>>(z1, z2, partial);
    proj_kernel<<<128, 256, 0, stream>>>(z1, z2, W1, b1, partial, pTh2, pbh2);
    pair_kernel<<<1024, 256, 0, stream>>>(pTh2, pbh2, W2, b2, out);
}